// Round 1
// baseline (181.599 us; speedup 1.0000x reference)
//
#include <hip/hip_runtime.h>
#include <hip/hip_bf16.h>

typedef _Float16 f16x8 __attribute__((ext_vector_type(8)));
typedef float f32x4 __attribute__((ext_vector_type(4)));

#define T_DIM 2048
#define H_DIM 2048
#define N_HEADS 16
#define DH 128
#define KBLK 50
#define NBLK 41
#define NEGV (-1.0e9f)
#define QSCALE 0.08838834764831845f  // 128^-0.5

__device__ __forceinline__ void gl_lds16(const void* g, void* l) {
    __builtin_amdgcn_global_load_lds(
        (const __attribute__((address_space(1))) void*)g,
        (__attribute__((address_space(3))) void*)l, 16, 0, 0);
}

// ---------------- convert x: fp32 -> fp16, straight copy ----------------
__global__ __launch_bounds__(256) void convert_x_kernel(const float* __restrict__ in,
                                                        _Float16* __restrict__ out) {
    int i = (blockIdx.x * 256 + threadIdx.x) * 8;
    float4 a = *(const float4*)&in[i];
    float4 b = *(const float4*)&in[i + 4];
    f16x8 o = {(_Float16)a.x, (_Float16)a.y, (_Float16)a.z, (_Float16)a.w,
               (_Float16)b.x, (_Float16)b.y, (_Float16)b.z, (_Float16)b.w};
    *(f16x8*)&out[i] = o;
}

// ------------- transpose 2048x2048 fp32 -> fp16 (out[j][i] = in[i][j]) -------------
__global__ __launch_bounds__(256) void transpose_kernel(const float* __restrict__ in,
                                                        _Float16* __restrict__ out) {
    __shared__ float tile[32][33];
    int bx = blockIdx.x * 32, by = blockIdx.y * 32;
    int tx = threadIdx.x, ty = threadIdx.y;  // 32 x 8
#pragma unroll
    for (int i = 0; i < 4; i++)
        tile[ty + i * 8][tx] = in[(size_t)(by + ty + i * 8) * H_DIM + bx + tx];
    __syncthreads();
#pragma unroll
    for (int i = 0; i < 4; i++)
        out[(size_t)(bx + ty + i * 8) * H_DIM + by + tx] = (_Float16)tile[tx][ty + i * 8];
}

// ---------------- GEMM: C = A(MxK f16 rm) * B, B given as BT (NxK f16 rm) ----------------
// 128x128 tile, BK=32, 256 threads = 4 waves, each wave 64x64 via 4x4 mfma_16x16x32_f16.
// MODE 0: write q/k/v fp16 [tensor][e][t][f], scale q by QSCALE. MODE 1: write fp32 row-major.
template <int MODE>
__global__ __launch_bounds__(256) void gemm_kernel(const _Float16* __restrict__ A,
                                                   const _Float16* __restrict__ BT,
                                                   void* __restrict__ Cout,
                                                   int M, int N, int K) {
    __shared__ _Float16 As[128 * 32];
    __shared__ _Float16 Bs[128 * 32];
    int tid = threadIdx.x;
    int lane = tid & 63, wave = tid >> 6;
    int bm = blockIdx.y * 128, bn = blockIdx.x * 128;
    int wr = (wave >> 1) * 64, wc = (wave & 1) * 64;
    int cb = lane & 15, hi = lane >> 4;

    f32x4 acc[4][4];
#pragma unroll
    for (int m = 0; m < 4; m++)
#pragma unroll
        for (int n = 0; n < 4; n++) acc[m][n] = (f32x4){0.f, 0.f, 0.f, 0.f};

    for (int k0 = 0; k0 < K; k0 += 32) {
        // stage: A tile 128x32 f16 = 8KB = 512 chunks of 16B; same for B. 2 chunks each per thread.
#pragma unroll
        for (int r = 0; r < 2; r++) {
            int c = tid + r * 256;
            int row = c >> 2, cc = c & 3;
            gl_lds16(&A[(size_t)(bm + row) * K + k0 + cc * 8], &As[c * 8]);
            gl_lds16(&BT[(size_t)(bn + row) * K + k0 + cc * 8], &Bs[c * 8]);
        }
        __syncthreads();
        f16x8 a[4], b[4];
#pragma unroll
        for (int m = 0; m < 4; m++)
            a[m] = *(const f16x8*)&As[(wr + m * 16 + cb) * 32 + hi * 8];
#pragma unroll
        for (int n = 0; n < 4; n++)
            b[n] = *(const f16x8*)&Bs[(wc + n * 16 + cb) * 32 + hi * 8];
#pragma unroll
        for (int m = 0; m < 4; m++)
#pragma unroll
            for (int n = 0; n < 4; n++)
                acc[m][n] = __builtin_amdgcn_mfma_f32_16x16x32_f16(a[m], b[n], acc[m][n], 0, 0, 0);
        __syncthreads();
    }

    if (MODE == 0) {
        _Float16* qkv = (_Float16*)Cout;
#pragma unroll
        for (int m = 0; m < 4; m++) {
#pragma unroll
            for (int n = 0; n < 4; n++) {
                int gn = bn + wc + n * 16 + cb;
                int tensor = gn >> 11;
                int ef = gn & 2047;
                int e = ef >> 7, f = ef & 127;
                float scale = (tensor == 0) ? QSCALE : 1.0f;
                _Float16* base = qkv + (size_t)tensor * (T_DIM * H_DIM) + (size_t)e * (T_DIM * DH) + f;
#pragma unroll
                for (int r = 0; r < 4; r++) {
                    int gm = bm + wr + m * 16 + hi * 4 + r;
                    base[(size_t)gm * DH] = (_Float16)(acc[m][n][r] * scale);
                }
            }
        }
    } else {
        float* C = (float*)Cout;
#pragma unroll
        for (int m = 0; m < 4; m++)
#pragma unroll
            for (int n = 0; n < 4; n++) {
                int gn = bn + wc + n * 16 + cb;
#pragma unroll
                for (int r = 0; r < 4; r++) {
                    int gm = bm + wr + m * 16 + hi * 4 + r;
                    C[(size_t)gm * N + gn] = acc[m][n][r];
                }
            }
    }
}

// ---------------- per-(block,head) attention ----------------
// grid = 41*16 blocks, 256 threads (4 waves). Wave w owns query rows [w*16, w*16+16).
__global__ __launch_bounds__(256) void attn_kernel(const _Float16* __restrict__ qkvb,
                                                   const float* __restrict__ bias,
                                                   const float* __restrict__ mask,
                                                   _Float16* __restrict__ aout) {
    int bid = blockIdx.x;
    int n = bid >> 4, e = bid & 15;
    int t0 = n * KBLK;
    int valid = (T_DIM - t0 < KBLK) ? (T_DIM - t0) : KBLK;

    __shared__ _Float16 Qs[64 * 136];
    __shared__ _Float16 Ks[64 * 136];
    __shared__ _Float16 VTs[128 * 72];
    __shared__ _Float16 Ps[64 * 72];
    __shared__ float maskv[64];

    int tid = threadIdx.x;
    int lane = tid & 63, wave = tid >> 6;
    const _Float16* qp = qkvb + (size_t)e * (T_DIM * DH);
    const _Float16* kp = qkvb + (size_t)(T_DIM * H_DIM) + (size_t)e * (T_DIM * DH);
    const _Float16* vp = qkvb + (size_t)2 * (T_DIM * H_DIM) + (size_t)e * (T_DIM * DH);

    // stage Q, K tiles (zero-padded to 64 rows)
#pragma unroll
    for (int i = 0; i < 4; i++) {
        int c = tid + i * 256;
        int r = c >> 4, c8 = c & 15;
        uint4 z = {0u, 0u, 0u, 0u};
        uint4 vq = z, vk = z;
        if (r < valid) {
            vq = *(const uint4*)&qp[(size_t)(t0 + r) * DH + c8 * 8];
            vk = *(const uint4*)&kp[(size_t)(t0 + r) * DH + c8 * 8];
        }
        *(uint4*)&Qs[r * 136 + c8 * 8] = vq;
        *(uint4*)&Ks[r * 136 + c8 * 8] = vk;
    }
    // stage V transposed: VTs[f][r]
#pragma unroll
    for (int i = 0; i < 32; i++) {
        int idx = tid + i * 256;
        int r = idx >> 7, f = idx & 127;
        VTs[f * 72 + r] = (r < valid) ? vp[(size_t)(t0 + r) * DH + f] : (_Float16)0.f;
    }
    if (tid < 64) maskv[tid] = (tid < valid) ? mask[t0 + tid] : NEGV;
    __syncthreads();

    int qr0 = wave * 16;
    int cb = lane & 15, hi = lane >> 4;

    // S = Q K^T  (64 padded rows x 64 padded cols), wave handles 16 q-rows
    f16x8 aq[4];
#pragma unroll
    for (int ks = 0; ks < 4; ks++)
        aq[ks] = *(const f16x8*)&Qs[(qr0 + cb) * 136 + ks * 32 + hi * 8];
    f32x4 s[4];
#pragma unroll
    for (int kt = 0; kt < 4; kt++) s[kt] = (f32x4){0.f, 0.f, 0.f, 0.f};
#pragma unroll
    for (int kt = 0; kt < 4; kt++)
#pragma unroll
        for (int ks = 0; ks < 4; ks++) {
            f16x8 bk = *(const f16x8*)&Ks[(kt * 16 + cb) * 136 + ks * 32 + hi * 8];
            s[kt] = __builtin_amdgcn_mfma_f32_16x16x32_f16(aq[ks], bk, s[kt], 0, 0, 0);
        }

    // bias + mask + softmax (row-wise over the 64 padded cols; pads forced to NEG)
#pragma unroll
    for (int r = 0; r < 4; r++) {
        int rl = qr0 + hi * 4 + r;
        int qi = t0 + rl;
        float mq = maskv[rl];
        float lg[4];
        float mx = -3.4e38f;
#pragma unroll
        for (int kt = 0; kt < 4; kt++) {
            int cl = kt * 16 + cb, ki = t0 + cl;
            float bg = (qi < T_DIM && ki < T_DIM)
                           ? bias[((size_t)e * T_DIM + qi) * T_DIM + ki] : 0.f;
            float pr = mq * maskv[cl];
            float v = s[kt][r] + bg + (pr > 0.f ? 0.f : NEGV);
            lg[kt] = v;
            mx = fmaxf(mx, v);
        }
#pragma unroll
        for (int off = 8; off; off >>= 1) mx = fmaxf(mx, __shfl_xor(mx, off));
        float sum = 0.f;
#pragma unroll
        for (int kt = 0; kt < 4; kt++) {
            float pe = __expf(lg[kt] - mx);
            lg[kt] = pe;
            sum += pe;
        }
#pragma unroll
        for (int off = 8; off; off >>= 1) sum += __shfl_xor(sum, off);
        float inv = 1.f / sum;
#pragma unroll
        for (int kt = 0; kt < 4; kt++)
            Ps[rl * 72 + kt * 16 + cb] = (_Float16)(lg[kt] * inv);
    }
    __syncthreads();

    // O = P V   (reduction over 64 padded keys), write fp16 [t][e*128+f]
    f16x8 pa[2];
#pragma unroll
    for (int ks = 0; ks < 2; ks++)
        pa[ks] = *(const f16x8*)&Ps[(qr0 + cb) * 72 + ks * 32 + hi * 8];
#pragma unroll
    for (int ft = 0; ft < 8; ft++) {
        f32x4 o = (f32x4){0.f, 0.f, 0.f, 0.f};
#pragma unroll
        for (int ks = 0; ks < 2; ks++) {
            f16x8 bv = *(const f16x8*)&VTs[(ft * 16 + cb) * 72 + ks * 32 + hi * 8];
            o = __builtin_amdgcn_mfma_f32_16x16x32_f16(pa[ks], bv, o, 0, 0, 0);
        }
#pragma unroll
        for (int r = 0; r < 4; r++) {
            int rl = qr0 + hi * 4 + r;
            if (rl < valid)
                aout[(size_t)(t0 + rl) * H_DIM + e * DH + ft * 16 + cb] = (_Float16)o[r];
        }
    }
}

extern "C" void kernel_launch(void* const* d_in, const int* in_sizes, int n_in,
                              void* d_out, int out_size, void* d_ws, size_t ws_size,
                              hipStream_t stream) {
    const float* x    = (const float*)d_in[0];
    const float* mask = (const float*)d_in[1];
    const float* bias = (const float*)d_in[2];
    const float* Wq   = (const float*)d_in[3];
    const float* Wk   = (const float*)d_in[4];
    const float* Wv   = (const float*)d_in[5];
    const float* Wo   = (const float*)d_in[6];
    float* out = (float*)d_out;

    // workspace layout (fp16): xb[4M] | WT[12M] | WoT[4M] | qkv[12M] | aout[4M]  = 72MB
    _Float16* xb   = (_Float16*)d_ws;
    _Float16* WT   = xb + (size_t)T_DIM * H_DIM;
    _Float16* WoT  = WT + (size_t)3 * T_DIM * H_DIM;
    _Float16* qkvb = WoT + (size_t)T_DIM * H_DIM;
    _Float16* aout = qkvb + (size_t)3 * T_DIM * H_DIM;

    convert_x_kernel<<<(T_DIM * H_DIM) / (256 * 8), 256, 0, stream>>>(x, xb);

    dim3 tb(32, 8), tg(64, 64);
    transpose_kernel<<<tg, tb, 0, stream>>>(Wq, WT);
    transpose_kernel<<<tg, tb, 0, stream>>>(Wk, WT + (size_t)T_DIM * H_DIM);
    transpose_kernel<<<tg, tb, 0, stream>>>(Wv, WT + (size_t)2 * T_DIM * H_DIM);
    transpose_kernel<<<tg, tb, 0, stream>>>(Wo, WoT);

    // fused QKV projection: A = xb (2048x2048), BT = WT (6144x2048)
    gemm_kernel<0><<<dim3(6144 / 128, T_DIM / 128), 256, 0, stream>>>(
        xb, WT, (void*)qkvb, T_DIM, 3 * H_DIM, H_DIM);

    attn_kernel<<<NBLK * N_HEADS, 256, 0, stream>>>(qkvb, bias, mask, aout);

    // output projection: A = aout (2048x2048), BT = WoT (2048x2048), C = fp32 out
    gemm_kernel<1><<<dim3(H_DIM / 128, T_DIM / 128), 256, 0, stream>>>(
        aout, WoT, (void*)out, T_DIM, H_DIM, H_DIM);
}

// Round 2
// 141.915 us; speedup vs baseline: 1.2796x; 1.2796x over previous
//
#include <hip/hip_runtime.h>
#include <hip/hip_bf16.h>

typedef _Float16 f16x8 __attribute__((ext_vector_type(8)));
typedef float f32x4 __attribute__((ext_vector_type(4)));

#define T_DIM 2048
#define H_DIM 2048
#define N_HEADS 16
#define DH 128
#define KBLK 50
#define NBLK 41
#define NEGV (-1.0e9f)
#define QSCALE 0.08838834764831845f  // 128^-0.5

__device__ __forceinline__ void gl_lds16(const void* g, void* l) {
    __builtin_amdgcn_global_load_lds(
        (const __attribute__((address_space(1))) void*)g,
        (__attribute__((address_space(3))) void*)l, 16, 0, 0);
}

// ---- fused prep: z<4 -> transpose weight fp32->fp16; z==4 -> convert x fp32->fp16 ----
__global__ __launch_bounds__(256) void prep_kernel(const float* __restrict__ x,
                                                   const float* __restrict__ Wq,
                                                   const float* __restrict__ Wk,
                                                   const float* __restrict__ Wv,
                                                   const float* __restrict__ Wo,
                                                   _Float16* __restrict__ xb,
                                                   _Float16* __restrict__ WT,
                                                   _Float16* __restrict__ WoT) {
    __shared__ float tile[32][33];
    int z = blockIdx.z;
    const float* src = (z == 0) ? Wq : (z == 1) ? Wk : (z == 2) ? Wv : (z == 3) ? Wo : x;
    _Float16* dst = (z == 3) ? WoT : (z == 4) ? xb : (WT + (size_t)z * T_DIM * H_DIM);
    int bx = blockIdx.x * 32, by = blockIdx.y * 32;
    int tx = threadIdx.x, ty = threadIdx.y;  // 32 x 8
    if (z == 4) {
#pragma unroll
        for (int i = 0; i < 4; i++) {
            int r = by + ty + i * 8;
            dst[(size_t)r * H_DIM + bx + tx] = (_Float16)src[(size_t)r * H_DIM + bx + tx];
        }
    } else {
#pragma unroll
        for (int i = 0; i < 4; i++)
            tile[ty + i * 8][tx] = src[(size_t)(by + ty + i * 8) * H_DIM + bx + tx];
        __syncthreads();
#pragma unroll
        for (int i = 0; i < 4; i++)
            dst[(size_t)(bx + ty + i * 8) * H_DIM + by + tx] = (_Float16)tile[tx][ty + i * 8];
    }
}

// ---------------- GEMM: C = A(MxK f16 rm) * B, B given as BT (NxK f16 rm) ----------------
// BM=128 x BN tile, BK=32, 256 threads = 4 waves. Double-buffered LDS with prefetch-
// before-compute (T3 minimum 2-phase): one __syncthreads per K-step.
// MODE 0: write q/k/v fp16 [tensor][e][t][f], scale q by QSCALE. MODE 1: write fp32 rm.
template <int MODE, int BN>
__global__ __launch_bounds__(256) void gemm_kernel(const _Float16* __restrict__ A,
                                                   const _Float16* __restrict__ BT,
                                                   void* __restrict__ Cout,
                                                   int M, int N, int K) {
    constexpr int BM = 128, BK = 32;
    constexpr int NB = BN / 32;  // N-frags per wave
    __shared__ _Float16 As[2][BM * BK];
    __shared__ _Float16 Bs[2][BN * BK];
    int tid = threadIdx.x;
    int lane = tid & 63, wave = tid >> 6;
    int bm = blockIdx.y * BM, bn = blockIdx.x * BN;
    int wr = (wave >> 1) * 64, wc = (wave & 1) * (BN / 2);
    int cb = lane & 15, hi = lane >> 4;

    f32x4 acc[4][NB];
#pragma unroll
    for (int m = 0; m < 4; m++)
#pragma unroll
        for (int n = 0; n < NB; n++) acc[m][n] = (f32x4){0.f, 0.f, 0.f, 0.f};

    auto stage = [&](int t, int buf) {
        int k0 = t * BK;
#pragma unroll
        for (int r = 0; r < (BM * BK / 8) / 256; r++) {
            int c = tid + r * 256;
            int row = c >> 2, cc = c & 3;  // BK/8 = 4 chunks/row
            gl_lds16(&A[(size_t)(bm + row) * K + k0 + cc * 8], &As[buf][c * 8]);
        }
#pragma unroll
        for (int r = 0; r < (BN * BK / 8) / 256; r++) {
            int c = tid + r * 256;
            int row = c >> 2, cc = c & 3;
            gl_lds16(&BT[(size_t)(bn + row) * K + k0 + cc * 8], &Bs[buf][c * 8]);
        }
    };

    const int NT = K / BK;
    stage(0, 0);
    __syncthreads();
    int cur = 0;
    for (int t = 0; t < NT; t++) {
        if (t + 1 < NT) stage(t + 1, cur ^ 1);
        f16x8 a[4], b[NB];
#pragma unroll
        for (int m = 0; m < 4; m++)
            a[m] = *(const f16x8*)&As[cur][(wr + m * 16 + cb) * BK + hi * 8];
#pragma unroll
        for (int n = 0; n < NB; n++)
            b[n] = *(const f16x8*)&Bs[cur][(wc + n * 16 + cb) * BK + hi * 8];
#pragma unroll
        for (int m = 0; m < 4; m++)
#pragma unroll
            for (int n = 0; n < NB; n++)
                acc[m][n] = __builtin_amdgcn_mfma_f32_16x16x32_f16(a[m], b[n], acc[m][n], 0, 0, 0);
        __syncthreads();
        cur ^= 1;
    }

    if (MODE == 0) {
        _Float16* qkv = (_Float16*)Cout;
#pragma unroll
        for (int m = 0; m < 4; m++) {
#pragma unroll
            for (int n = 0; n < NB; n++) {
                int gn = bn + wc + n * 16 + cb;
                int tensor = gn >> 11;
                int ef = gn & 2047;
                int e = ef >> 7, f = ef & 127;
                float scale = (tensor == 0) ? QSCALE : 1.0f;
                _Float16* base = qkv + (size_t)tensor * (T_DIM * H_DIM) + (size_t)e * (T_DIM * DH) + f;
#pragma unroll
                for (int r = 0; r < 4; r++) {
                    int gm = bm + wr + m * 16 + hi * 4 + r;
                    base[(size_t)gm * DH] = (_Float16)(acc[m][n][r] * scale);
                }
            }
        }
    } else {
        float* C = (float*)Cout;
#pragma unroll
        for (int m = 0; m < 4; m++)
#pragma unroll
            for (int n = 0; n < NB; n++) {
                int gn = bn + wc + n * 16 + cb;
#pragma unroll
                for (int r = 0; r < 4; r++) {
                    int gm = bm + wr + m * 16 + hi * 4 + r;
                    C[(size_t)gm * N + gn] = acc[m][n][r];
                }
            }
    }
}

// ---------------- per-(block,head) attention ----------------
// grid = 41*16 blocks, 256 threads (4 waves). Wave w owns query rows [w*16, w*16+16).
__global__ __launch_bounds__(256) void attn_kernel(const _Float16* __restrict__ qkvb,
                                                   const float* __restrict__ bias,
                                                   const float* __restrict__ mask,
                                                   _Float16* __restrict__ aout) {
    int bid = blockIdx.x;
    int n = bid >> 4, e = bid & 15;
    int t0 = n * KBLK;
    int valid = (T_DIM - t0 < KBLK) ? (T_DIM - t0) : KBLK;

    __shared__ _Float16 Qs[64 * 136];
    __shared__ _Float16 Ks[64 * 136];
    __shared__ _Float16 VTs[128 * 72];
    __shared__ _Float16 Ps[64 * 72];
    __shared__ float maskv[64];

    int tid = threadIdx.x;
    int lane = tid & 63, wave = tid >> 6;
    const _Float16* qp = qkvb + (size_t)e * (T_DIM * DH);
    const _Float16* kp = qkvb + (size_t)(T_DIM * H_DIM) + (size_t)e * (T_DIM * DH);
    const _Float16* vp = qkvb + (size_t)2 * (T_DIM * H_DIM) + (size_t)e * (T_DIM * DH);

    // stage Q, K tiles (zero-padded to 64 rows), vectorized
#pragma unroll
    for (int i = 0; i < 4; i++) {
        int c = tid + i * 256;
        int r = c >> 4, c8 = c & 15;
        uint4 z = {0u, 0u, 0u, 0u};
        uint4 vq = z, vk = z;
        if (r < valid) {
            vq = *(const uint4*)&qp[(size_t)(t0 + r) * DH + c8 * 8];
            vk = *(const uint4*)&kp[(size_t)(t0 + r) * DH + c8 * 8];
        }
        *(uint4*)&Qs[r * 136 + c8 * 8] = vq;
        *(uint4*)&Ks[r * 136 + c8 * 8] = vk;
    }
    // stage V transposed, vectorized: 16B loads, lane-consecutive-row LDS writes (conflict-free)
#pragma unroll
    for (int i = 0; i < 4; i++) {
        int c = tid + i * 256;
        int r = c & 63;
        int f0 = (c >> 6) * 8;
        uint4 v = {0u, 0u, 0u, 0u};
        if (r < valid) v = *(const uint4*)&vp[(size_t)(t0 + r) * DH + f0];
        _Float16 tmp[8];
        *(uint4*)tmp = v;
#pragma unroll
        for (int j = 0; j < 8; j++) VTs[(f0 + j) * 72 + r] = tmp[j];
    }
    if (tid < 64) maskv[tid] = (tid < valid) ? mask[t0 + tid] : NEGV;
    __syncthreads();

    int qr0 = wave * 16;
    int cb = lane & 15, hi = lane >> 4;

    // S = Q K^T  (64 padded rows x 64 padded cols), wave handles 16 q-rows
    f16x8 aq[4];
#pragma unroll
    for (int ks = 0; ks < 4; ks++)
        aq[ks] = *(const f16x8*)&Qs[(qr0 + cb) * 136 + ks * 32 + hi * 8];
    f32x4 s[4];
#pragma unroll
    for (int kt = 0; kt < 4; kt++) s[kt] = (f32x4){0.f, 0.f, 0.f, 0.f};
#pragma unroll
    for (int kt = 0; kt < 4; kt++)
#pragma unroll
        for (int ks = 0; ks < 4; ks++) {
            f16x8 bk = *(const f16x8*)&Ks[(kt * 16 + cb) * 136 + ks * 32 + hi * 8];
            s[kt] = __builtin_amdgcn_mfma_f32_16x16x32_f16(aq[ks], bk, s[kt], 0, 0, 0);
        }

    // bias + mask + softmax (row-wise over the 64 padded cols; pads forced to NEG)
#pragma unroll
    for (int r = 0; r < 4; r++) {
        int rl = qr0 + hi * 4 + r;
        int qi = t0 + rl;
        float mq = maskv[rl];
        float lg[4];
        float mx = -3.4e38f;
#pragma unroll
        for (int kt = 0; kt < 4; kt++) {
            int cl = kt * 16 + cb, ki = t0 + cl;
            float bg = (qi < T_DIM && ki < T_DIM)
                           ? bias[((size_t)e * T_DIM + qi) * T_DIM + ki] : 0.f;
            float pr = mq * maskv[cl];
            float v = s[kt][r] + bg + (pr > 0.f ? 0.f : NEGV);
            lg[kt] = v;
            mx = fmaxf(mx, v);
        }
#pragma unroll
        for (int off = 8; off; off >>= 1) mx = fmaxf(mx, __shfl_xor(mx, off));
        float sum = 0.f;
#pragma unroll
        for (int kt = 0; kt < 4; kt++) {
            float pe = __expf(lg[kt] - mx);
            lg[kt] = pe;
            sum += pe;
        }
#pragma unroll
        for (int off = 8; off; off >>= 1) sum += __shfl_xor(sum, off);
        float inv = 1.f / sum;
#pragma unroll
        for (int kt = 0; kt < 4; kt++)
            Ps[rl * 72 + kt * 16 + cb] = (_Float16)(lg[kt] * inv);
    }
    __syncthreads();

    // O = P V   (reduction over 64 padded keys), write fp16 [t][e*128+f]
    f16x8 pa[2];
#pragma unroll
    for (int ks = 0; ks < 2; ks++)
        pa[ks] = *(const f16x8*)&Ps[(qr0 + cb) * 72 + ks * 32 + hi * 8];
#pragma unroll
    for (int ft = 0; ft < 8; ft++) {
        f32x4 o = (f32x4){0.f, 0.f, 0.f, 0.f};
#pragma unroll
        for (int ks = 0; ks < 2; ks++) {
            f16x8 bv = *(const f16x8*)&VTs[(ft * 16 + cb) * 72 + ks * 32 + hi * 8];
            o = __builtin_amdgcn_mfma_f32_16x16x32_f16(pa[ks], bv, o, 0, 0, 0);
        }
#pragma unroll
        for (int r = 0; r < 4; r++) {
            int rl = qr0 + hi * 4 + r;
            if (rl < valid)
                aout[(size_t)(t0 + rl) * H_DIM + e * DH + ft * 16 + cb] = (_Float16)o[r];
        }
    }
}

extern "C" void kernel_launch(void* const* d_in, const int* in_sizes, int n_in,
                              void* d_out, int out_size, void* d_ws, size_t ws_size,
                              hipStream_t stream) {
    const float* x    = (const float*)d_in[0];
    const float* mask = (const float*)d_in[1];
    const float* bias = (const float*)d_in[2];
    const float* Wq   = (const float*)d_in[3];
    const float* Wk   = (const float*)d_in[4];
    const float* Wv   = (const float*)d_in[5];
    const float* Wo   = (const float*)d_in[6];
    float* out = (float*)d_out;

    // workspace layout (fp16): xb[4M] | WT[12M] | WoT[4M] | qkv[12M] | aout[4M]  = 72MB
    _Float16* xb   = (_Float16*)d_ws;
    _Float16* WT   = xb + (size_t)T_DIM * H_DIM;
    _Float16* WoT  = WT + (size_t)3 * T_DIM * H_DIM;
    _Float16* qkvb = WoT + (size_t)T_DIM * H_DIM;
    _Float16* aout = qkvb + (size_t)3 * T_DIM * H_DIM;

    prep_kernel<<<dim3(64, 64, 5), dim3(32, 8), 0, stream>>>(x, Wq, Wk, Wv, Wo, xb, WT, WoT);

    // fused QKV projection: A = xb (2048x2048), BT = WT (6144x2048)
    gemm_kernel<0, 128><<<dim3(6144 / 128, T_DIM / 128), 256, 0, stream>>>(
        xb, WT, (void*)qkvb, T_DIM, 3 * H_DIM, H_DIM);

    attn_kernel<<<NBLK * N_HEADS, 256, 0, stream>>>(qkvb, bias, mask, aout);

    // output projection: A = aout (2048x2048), BT = WoT (2048x2048), C = fp32 out
    gemm_kernel<1, 64><<<dim3(H_DIM / 64, T_DIM / 128), 256, 0, stream>>>(
        aout, WoT, (void*)out, T_DIM, H_DIM, H_DIM);
}